// Round 1
// baseline (205.973 us; speedup 1.0000x reference)
//
#include <hip/hip_runtime.h>

#define CB 4
#define CIN 256
#define COUT 256
#define HH 80
#define WW 80
#define HW (HH*WW)
#define K2 9
#define NKC 72          // K chunks = 2304/32
#define LDSROW 56       // padded B-tile row stride (elements), 112B: 16B-aligned, ~2-way banks

typedef unsigned short ushort_t;
typedef __attribute__((ext_vector_type(8))) short bf16x8;
typedef __attribute__((ext_vector_type(4))) float f32x4;

__device__ __forceinline__ ushort_t f2bf(float f) {
    unsigned int b = __float_as_uint(f);
    b += 0x7fffu + ((b >> 16) & 1u);
    return (ushort_t)(b >> 16);
}

__device__ __forceinline__ float bflo(unsigned int u) { return __uint_as_float(u << 16); }
__device__ __forceinline__ float bfhi(unsigned int u) { return __uint_as_float(u & 0xffff0000u); }

__device__ __forceinline__ unsigned int blendpack(unsigned int a, unsigned int b,
                                                  unsigned int c, unsigned int d,
                                                  float w0, float w1, float w2, float w3) {
    float lo = w0*bflo(a) + w1*bflo(b) + w2*bflo(c) + w3*bflo(d);
    float hi = w0*bfhi(a) + w1*bfhi(b) + w2*bfhi(c) + w3*bfhi(d);
    unsigned int r;
    asm("v_cvt_pk_bf16_f32 %0, %1, %2" : "=v"(r) : "v"(lo), "v"(hi));
    return r;
}

// NCHW fp32 -> NHWC bf16
__global__ __launch_bounds__(256) void transpose_x(const float* __restrict__ x,
                                                   ushort_t* __restrict__ xb) {
    const int b = blockIdx.x / (HW/64);
    const int hw0 = (blockIdx.x % (HW/64)) * 64;
    const int c = threadIdx.x;
    const float* xp = x + ((size_t)b*CIN + c)*HW + hw0;
    ushort_t* op = xb + ((size_t)b*HW + hw0)*CIN + c;
    #pragma unroll 4
    for (int i = 0; i < 64; ++i)
        op[(size_t)i*CIN] = f2bf(xp[i]);
}

// Pack conv_w and offset_w into MFMA A-fragment order.
// K-order: kglob = tap*256 + c. Fragment: lane l holds A[mt*16+(l&15)][kc*32+(l>>4)*8+i]
__global__ __launch_bounds__(256) void pack_w(const float* __restrict__ conv_w,
                                              const float* __restrict__ offset_w,
                                              ushort_t* __restrict__ wmain,
                                              ushort_t* __restrict__ woff) {
    const int t = blockIdx.x * 256 + threadIdx.x;
    if (t < NKC*16*64) {
        const int kc = t >> 10;
        const int mt = (t >> 6) & 15;
        const int l  = t & 63;
        const int m  = mt*16 + (l & 15);
        const int kb = kc*32 + ((l >> 4) << 3);
        ushort_t v[8];
        #pragma unroll
        for (int i = 0; i < 8; ++i) {
            const int kg = kb + i;
            const int tap = kg >> 8;
            const int c = kg & 255;
            v[i] = f2bf(conv_w[(size_t)(m*CIN + c)*K2 + tap]);
        }
        uint4 r;
        r.x = v[0] | ((unsigned)v[1] << 16);
        r.y = v[2] | ((unsigned)v[3] << 16);
        r.z = v[4] | ((unsigned)v[5] << 16);
        r.w = v[6] | ((unsigned)v[7] << 16);
        *(uint4*)&wmain[(size_t)t*8] = r;
    } else if (t < NKC*16*64 + NKC*2*64) {
        const int t2 = t - NKC*16*64;
        const int kc = t2 >> 7;
        const int mt = (t2 >> 6) & 1;
        const int l  = t2 & 63;
        const int m  = mt*16 + (l & 15);
        const int kb = kc*32 + ((l >> 4) << 3);
        ushort_t v[8];
        #pragma unroll
        for (int i = 0; i < 8; ++i) {
            const int kg = kb + i;
            const int tap = kg >> 8;
            const int c = kg & 255;
            v[i] = (m < 18) ? f2bf(offset_w[(size_t)(m*CIN + c)*K2 + tap]) : (ushort_t)0;
        }
        uint4 r;
        r.x = v[0] | ((unsigned)v[1] << 16);
        r.y = v[2] | ((unsigned)v[3] << 16);
        r.z = v[4] | ((unsigned)v[5] << 16);
        r.w = v[6] | ((unsigned)v[7] << 16);
        *(uint4*)&woff[(size_t)t2*8] = r;
    }
}

__device__ __forceinline__ void gather_chunk(const ushort_t* __restrict__ xbase, int kc,
                                             ushort_t* __restrict__ lbuf,
                                             const float (&bw)[K2][64][4],
                                             const int (&bi)[K2][64][4], int tid) {
    const int px = tid >> 2, cg = tid & 3;
    const int tap = kc >> 3;
    const int c0 = (kc & 7)*32 + cg*8;
    const float4 wt = *(const float4*)bw[tap][px];
    const int4  ix = *(const int4*)bi[tap][px];
    const uint4 va = *(const uint4*)(xbase + ix.x + c0);
    const uint4 vb = *(const uint4*)(xbase + ix.y + c0);
    const uint4 vc = *(const uint4*)(xbase + ix.z + c0);
    const uint4 vd = *(const uint4*)(xbase + ix.w + c0);
    uint4 r;
    r.x = blendpack(va.x, vb.x, vc.x, vd.x, wt.x, wt.y, wt.z, wt.w);
    r.y = blendpack(va.y, vb.y, vc.y, vd.y, wt.x, wt.y, wt.z, wt.w);
    r.z = blendpack(va.z, vb.z, vc.z, vd.z, wt.x, wt.y, wt.z, wt.w);
    r.w = blendpack(va.w, vb.w, vc.w, vd.w, wt.x, wt.y, wt.z, wt.w);
    *(uint4*)&lbuf[px*LDSROW + cg*8] = r;
}

__global__ __launch_bounds__(256) void deform_main(const ushort_t* __restrict__ xb,
                                                   const ushort_t* __restrict__ wmain,
                                                   const ushort_t* __restrict__ woff,
                                                   const float* __restrict__ offset_b,
                                                   const float* __restrict__ conv_b,
                                                   float* __restrict__ out) {
    __shared__ ushort_t ldsB[2][64*LDSROW];
    __shared__ float off_lds[18][64];
    __shared__ float bw[K2][64][4];
    __shared__ int   bi[K2][64][4];

    const int tid = threadIdx.x;
    const int lane = tid & 63;
    const int wv = tid >> 6;
    const int bid = blockIdx.x;
    const int bb = bid / (HW/64);
    const int hwb = (bid % (HW/64)) * 64;
    const ushort_t* xbase = xb + (size_t)bb * HW * CIN;

    // ---------- phase 1: offset conv (M padded 18->32), im2col GEMM ----------
    {
        const int mt = wv >> 1;          // 0..1
        const int nt0 = (wv & 1) * 2;    // 0 or 2
        f32x4 a0 = {0.f,0.f,0.f,0.f}, a1 = {0.f,0.f,0.f,0.f};
        const int px = tid >> 2, cg = tid & 3;
        const int hw = hwb + px;
        const int ph = hw / WW, pw = hw - ph*WW;
        for (int kc = 0; kc < NKC; ++kc) {
            {
                const int tap = kc >> 3;
                const int c0 = (kc & 7)*32 + cg*8;
                const int yy = ph + tap/3 - 1;
                const int xx = pw + tap%3 - 1;
                uint4 v = make_uint4(0u,0u,0u,0u);
                if (yy >= 0 && yy < HH && xx >= 0 && xx < WW)
                    v = *(const uint4*)(xbase + (yy*WW + xx)*CIN + c0);
                *(uint4*)&ldsB[0][px*LDSROW + cg*8] = v;
            }
            __syncthreads();
            const bf16x8 af = *(const bf16x8*)(woff + ((size_t)(kc*2 + mt)*64 + lane)*8);
            const bf16x8 bf0 = *(const bf16x8*)&ldsB[0][(nt0*16 + (lane&15))*LDSROW + (lane>>4)*8];
            const bf16x8 bf1 = *(const bf16x8*)&ldsB[0][((nt0+1)*16 + (lane&15))*LDSROW + (lane>>4)*8];
            a0 = __builtin_amdgcn_mfma_f32_16x16x32_bf16(af, bf0, a0, 0, 0, 0);
            a1 = __builtin_amdgcn_mfma_f32_16x16x32_bf16(af, bf1, a1, 0, 0, 0);
            __syncthreads();
        }
        const int r0 = (lane >> 4) * 4;
        #pragma unroll
        for (int j = 0; j < 4; ++j) {
            const int oc = mt*16 + r0 + j;
            if (oc < 18) {
                const float ob = offset_b[oc];
                off_lds[oc][nt0*16 + (lane & 15)]     = a0[j] + ob;
                off_lds[oc][(nt0+1)*16 + (lane & 15)] = a1[j] + ob;
            }
        }
    }
    __syncthreads();

    // ---------- phase 2: bilinear weights/indices ----------
    for (int it = tid; it < K2*64; it += 256) {
        const int tap = it >> 6, px = it & 63;
        const int hw = hwb + px;
        const int ph = hw / WW, pw = hw - ph*WW;
        const float dy = off_lds[tap*2][px];
        const float dx = off_lds[tap*2 + 1][px];
        const float py  = (float)(ph + tap/3 - 1) + dy;
        const float pxx = (float)(pw + tap%3 - 1) + dx;
        const float y0f = floorf(py), x0f = floorf(pxx);
        const float wy = py - y0f, wx = pxx - x0f;
        const int y0 = (int)y0f, x0 = (int)x0f;
        const int y1 = y0 + 1, x1 = x0 + 1;
        const float vy0 = (y0 >= 0 && y0 < HH) ? 1.f : 0.f;
        const float vy1 = (y1 >= 0 && y1 < HH) ? 1.f : 0.f;
        const float vx0 = (x0 >= 0 && x0 < WW) ? 1.f : 0.f;
        const float vx1 = (x1 >= 0 && x1 < WW) ? 1.f : 0.f;
        const int y0c = min(max(y0, 0), HH-1), y1c = min(max(y1, 0), HH-1);
        const int x0c = min(max(x0, 0), WW-1), x1c = min(max(x1, 0), WW-1);
        bw[tap][px][0] = (1.f-wy)*(1.f-wx)*vy0*vx0;
        bw[tap][px][1] = (1.f-wy)*wx*vy0*vx1;
        bw[tap][px][2] = wy*(1.f-wx)*vy1*vx0;
        bw[tap][px][3] = wy*wx*vy1*vx1;
        bi[tap][px][0] = (y0c*WW + x0c)*CIN;
        bi[tap][px][1] = (y0c*WW + x1c)*CIN;
        bi[tap][px][2] = (y1c*WW + x0c)*CIN;
        bi[tap][px][3] = (y1c*WW + x1c)*CIN;
    }
    __syncthreads();

    // ---------- phase 3: main deformable GEMM ----------
    f32x4 acc[4][4];
    #pragma unroll
    for (int mi = 0; mi < 4; ++mi)
        #pragma unroll
        for (int ni = 0; ni < 4; ++ni)
            acc[mi][ni] = (f32x4){0.f,0.f,0.f,0.f};

    const int mt0 = wv * 4;
    gather_chunk(xbase, 0, ldsB[0], bw, bi, tid);
    __syncthreads();
    for (int kc = 0; kc < NKC; ++kc) {
        const int cur = kc & 1;
        if (kc < NKC-1) gather_chunk(xbase, kc+1, ldsB[cur^1], bw, bi, tid);
        bf16x8 afr[4], bfr[4];
        #pragma unroll
        for (int mi = 0; mi < 4; ++mi)
            afr[mi] = *(const bf16x8*)(wmain + ((size_t)(kc*16 + mt0 + mi)*64 + lane)*8);
        #pragma unroll
        for (int ni = 0; ni < 4; ++ni)
            bfr[ni] = *(const bf16x8*)&ldsB[cur][(ni*16 + (lane&15))*LDSROW + (lane>>4)*8];
        #pragma unroll
        for (int mi = 0; mi < 4; ++mi)
            #pragma unroll
            for (int ni = 0; ni < 4; ++ni)
                acc[mi][ni] = __builtin_amdgcn_mfma_f32_16x16x32_bf16(afr[mi], bfr[ni], acc[mi][ni], 0, 0, 0);
        __syncthreads();
    }

    // epilogue: D[m][n]: col = lane&15 (pixel), row = (lane>>4)*4+j (out channel)
    #pragma unroll
    for (int mi = 0; mi < 4; ++mi) {
        #pragma unroll
        for (int ni = 0; ni < 4; ++ni) {
            const int pxl = ni*16 + (lane & 15);
            #pragma unroll
            for (int j = 0; j < 4; ++j) {
                const int o = (mt0 + mi)*16 + (lane >> 4)*4 + j;
                out[((size_t)bb*COUT + o)*HW + hwb + pxl] = acc[mi][ni][j] + conv_b[o];
            }
        }
    }
}

extern "C" void kernel_launch(void* const* d_in, const int* in_sizes, int n_in,
                              void* d_out, int out_size, void* d_ws, size_t ws_size,
                              hipStream_t stream) {
    const float* x        = (const float*)d_in[0];
    const float* offset_w = (const float*)d_in[1];
    const float* offset_b = (const float*)d_in[2];
    const float* conv_w   = (const float*)d_in[3];
    const float* conv_b   = (const float*)d_in[4];
    float* out = (float*)d_out;

    char* wsb = (char*)d_ws;
    ushort_t* xb    = (ushort_t*)wsb;                                   // 13,107,200 B
    ushort_t* wmain = (ushort_t*)(wsb + (size_t)CB*HW*CIN*2);           // 1,179,648 B
    ushort_t* woff  = (ushort_t*)(wsb + (size_t)CB*HW*CIN*2 + (size_t)NKC*16*64*8*2); // 147,456 B

    hipLaunchKernelGGL(transpose_x, dim3(CB*(HW/64)), dim3(256), 0, stream, x, xb);
    hipLaunchKernelGGL(pack_w, dim3(324), dim3(256), 0, stream, conv_w, offset_w, wmain, woff);
    hipLaunchKernelGGL(deform_main, dim3(CB*(HW/64)), dim3(256), 0, stream,
                       xb, wmain, woff, offset_b, conv_b, out);
}

// Round 3
// 177.959 us; speedup vs baseline: 1.1574x; 1.1574x over previous
//
#include <hip/hip_runtime.h>

#define CB 4
#define CIN 256
#define COUT 256
#define HH 80
#define WW 80
#define HW (HH*WW)
#define K2 9
#define NKC 72          // K chunks = 2304/32
#define LDSROW 56       // padded B-tile row stride (elements)

typedef unsigned short ushort_t;
typedef __attribute__((ext_vector_type(8))) short bf16x8;
typedef __attribute__((ext_vector_type(4))) float f32x4;

__device__ __forceinline__ ushort_t f2bf(float f) {
    unsigned int b = __float_as_uint(f);
    b += 0x7fffu + ((b >> 16) & 1u);
    return (ushort_t)(b >> 16);
}
__device__ __forceinline__ float bflo(unsigned int u) { return __uint_as_float(u << 16); }
__device__ __forceinline__ float bfhi(unsigned int u) { return __uint_as_float(u & 0xffff0000u); }

__device__ __forceinline__ unsigned int blendpack(unsigned int a, unsigned int b,
                                                  unsigned int c, unsigned int d,
                                                  float w0, float w1, float w2, float w3) {
    float lo = w0*bflo(a) + w1*bflo(b) + w2*bflo(c) + w3*bflo(d);
    float hi = w0*bfhi(a) + w1*bfhi(b) + w2*bfhi(c) + w3*bfhi(d);
    unsigned int r;
    asm("v_cvt_pk_bf16_f32 %0, %1, %2" : "=v"(r) : "v"(lo), "v"(hi));
    return r;
}

// NCHW fp32 -> NHWC bf16, LDS-tiled, XOR-swizzled (both-sides swizzle on 16B blocks)
__global__ __launch_bounds__(256) void transpose_x(const float* __restrict__ x,
                                                   ushort_t* __restrict__ xb) {
    __shared__ ushort_t tile[64*256];
    const int b = blockIdx.x / (HW/64);
    const int hw0 = (blockIdx.x % (HW/64)) * 64;
    const int tid = threadIdx.x;
    // read phase: lane groups of 16 read consecutive float4 along HW (coalesced)
    const int px4 = (tid & 15) * 4;
    const int cb0 = tid >> 4;            // 0..15
    const float* xp = x + (size_t)b*CIN*HW + hw0 + px4;
    #pragma unroll
    for (int p = 0; p < 16; ++p) {
        const int c = cb0 * 16 + p;
        const float4 v = *(const float4*)(xp + (size_t)c*HW);
        const int blk = c >> 3, sub = c & 7;
        tile[(px4+0)*256 + (((blk) ^ ((px4+0)&31))<<3) + sub] = f2bf(v.x);
        tile[(px4+1)*256 + (((blk) ^ ((px4+1)&31))<<3) + sub] = f2bf(v.y);
        tile[(px4+2)*256 + (((blk) ^ ((px4+2)&31))<<3) + sub] = f2bf(v.z);
        tile[(px4+3)*256 + (((blk) ^ ((px4+3)&31))<<3) + sub] = f2bf(v.w);
    }
    __syncthreads();
    // write phase: 32 lanes write 512B contiguous per pixel (coalesced)
    const int g = tid & 31;
    #pragma unroll
    for (int p = 0; p < 8; ++p) {
        const int px = (tid >> 5) + p*8;
        const uint4 r = *(const uint4*)&tile[px*256 + ((g ^ (px&31))<<3)];
        *(uint4*)&xb[((size_t)b*HW + hw0 + px)*CIN + g*8] = r;
    }
}

// Pack conv_w and offset_w into MFMA A-fragment order.
__global__ __launch_bounds__(256) void pack_w(const float* __restrict__ conv_w,
                                              const float* __restrict__ offset_w,
                                              ushort_t* __restrict__ wmain,
                                              ushort_t* __restrict__ woff) {
    const int t = blockIdx.x * 256 + threadIdx.x;
    if (t < NKC*16*64) {
        const int kc = t >> 10;
        const int mt = (t >> 6) & 15;
        const int l  = t & 63;
        const int m  = mt*16 + (l & 15);
        const int kb = kc*32 + ((l >> 4) << 3);
        ushort_t v[8];
        #pragma unroll
        for (int i = 0; i < 8; ++i) {
            const int kg = kb + i;
            const int tap = kg >> 8;
            const int c = kg & 255;
            v[i] = f2bf(conv_w[(size_t)(m*CIN + c)*K2 + tap]);
        }
        uint4 r;
        r.x = v[0] | ((unsigned)v[1] << 16);
        r.y = v[2] | ((unsigned)v[3] << 16);
        r.z = v[4] | ((unsigned)v[5] << 16);
        r.w = v[6] | ((unsigned)v[7] << 16);
        *(uint4*)&wmain[(size_t)t*8] = r;
    } else if (t < NKC*16*64 + NKC*2*64) {
        const int t2 = t - NKC*16*64;
        const int kc = t2 >> 7;
        const int mt = (t2 >> 6) & 1;
        const int l  = t2 & 63;
        const int m  = mt*16 + (l & 15);
        const int kb = kc*32 + ((l >> 4) << 3);
        ushort_t v[8];
        #pragma unroll
        for (int i = 0; i < 8; ++i) {
            const int kg = kb + i;
            const int tap = kg >> 8;
            const int c = kg & 255;
            v[i] = (m < 18) ? f2bf(offset_w[(size_t)(m*CIN + c)*K2 + tap]) : (ushort_t)0;
        }
        uint4 r;
        r.x = v[0] | ((unsigned)v[1] << 16);
        r.y = v[2] | ((unsigned)v[3] << 16);
        r.z = v[4] | ((unsigned)v[5] << 16);
        r.w = v[6] | ((unsigned)v[7] << 16);
        *(uint4*)&woff[(size_t)t2*8] = r;
    }
}

__global__ __launch_bounds__(256) void deform_main(const ushort_t* __restrict__ xb,
                                                   const ushort_t* __restrict__ wmain,
                                                   const ushort_t* __restrict__ woff,
                                                   const float* __restrict__ offset_b,
                                                   const float* __restrict__ conv_b,
                                                   float* __restrict__ out) {
    __shared__ ushort_t ldsB[2][64*LDSROW];
    __shared__ float off_lds[18][64];
    __shared__ float bw[K2][64][4];
    __shared__ int   bi[K2][64][4];

    const int tid = threadIdx.x;
    const int lane = tid & 63;
    const int wv = tid >> 6;
    const int bid = blockIdx.x;
    const int bb = bid / (HW/64);
    const int hwb = (bid % (HW/64)) * 64;
    const ushort_t* xbase = xb + (size_t)bb * HW * CIN;
    const int px = tid >> 2, cg = tid & 3;

    // ---------- phase 1: offset conv (M padded 18->32), double-buffered, 1 barrier/chunk ----------
    {
        const int mt = wv >> 1;          // 0..1
        const int nt0 = (wv & 1) * 2;    // 0 or 2
        f32x4 a0 = {0.f,0.f,0.f,0.f}, a1 = {0.f,0.f,0.f,0.f};
        const int hw = hwb + px;
        const int ph = hw / WW, pw = hw - ph*WW;

        uint4 v;
        {   // preload chunk 0
            const int yy = ph - 1, xx = pw - 1;
            v = make_uint4(0u,0u,0u,0u);
            if (yy >= 0 && yy < HH && xx >= 0 && xx < WW)
                v = *(const uint4*)(xbase + (yy*WW + xx)*CIN + cg*8);
        }
        for (int kc = 0; kc < NKC; ++kc) {
            const bf16x8 af = *(const bf16x8*)(woff + ((size_t)(kc*2 + mt)*64 + lane)*8);
            *(uint4*)&ldsB[kc&1][px*LDSROW + cg*8] = v;
            if (kc+1 < NKC) {
                const int tap = (kc+1) >> 3;
                const int c0 = ((kc+1) & 7)*32 + cg*8;
                const int yy = ph + tap/3 - 1;
                const int xx = pw + tap%3 - 1;
                uint4 nv = make_uint4(0u,0u,0u,0u);
                if (yy >= 0 && yy < HH && xx >= 0 && xx < WW)
                    nv = *(const uint4*)(xbase + (yy*WW + xx)*CIN + c0);
                v = nv;
            }
            asm volatile("s_waitcnt lgkmcnt(0)" ::: "memory");
            __builtin_amdgcn_s_barrier();
            const bf16x8 bf0 = *(const bf16x8*)&ldsB[kc&1][(nt0*16 + (lane&15))*LDSROW + (lane>>4)*8];
            const bf16x8 bf1 = *(const bf16x8*)&ldsB[kc&1][((nt0+1)*16 + (lane&15))*LDSROW + (lane>>4)*8];
            a0 = __builtin_amdgcn_mfma_f32_16x16x32_bf16(af, bf0, a0, 0, 0, 0);
            a1 = __builtin_amdgcn_mfma_f32_16x16x32_bf16(af, bf1, a1, 0, 0, 0);
        }
        const int r0 = (lane >> 4) * 4;
        #pragma unroll
        for (int j = 0; j < 4; ++j) {
            const int oc = mt*16 + r0 + j;
            if (oc < 18) {
                const float ob = offset_b[oc];
                off_lds[oc][nt0*16 + (lane & 15)]     = a0[j] + ob;
                off_lds[oc][(nt0+1)*16 + (lane & 15)] = a1[j] + ob;
            }
        }
    }
    __syncthreads();

    // ---------- phase 2: bilinear weights/indices ----------
    for (int it = tid; it < K2*64; it += 256) {
        const int tap = it >> 6, pxl = it & 63;
        const int hw = hwb + pxl;
        const int ph = hw / WW, pw = hw - ph*WW;
        const float dy = off_lds[tap*2][pxl];
        const float dx = off_lds[tap*2 + 1][pxl];
        const float py  = (float)(ph + tap/3 - 1) + dy;
        const float pxx = (float)(pw + tap%3 - 1) + dx;
        const float y0f = floorf(py), x0f = floorf(pxx);
        const float wy = py - y0f, wx = pxx - x0f;
        const int y0 = (int)y0f, x0 = (int)x0f;
        const int y1 = y0 + 1, x1 = x0 + 1;
        const float vy0 = (y0 >= 0 && y0 < HH) ? 1.f : 0.f;
        const float vy1 = (y1 >= 0 && y1 < HH) ? 1.f : 0.f;
        const float vx0 = (x0 >= 0 && x0 < WW) ? 1.f : 0.f;
        const float vx1 = (x1 >= 0 && x1 < WW) ? 1.f : 0.f;
        const int y0c = min(max(y0, 0), HH-1), y1c = min(max(y1, 0), HH-1);
        const int x0c = min(max(x0, 0), WW-1), x1c = min(max(x1, 0), WW-1);
        bw[tap][pxl][0] = (1.f-wy)*(1.f-wx)*vy0*vx0;
        bw[tap][pxl][1] = (1.f-wy)*wx*vy0*vx1;
        bw[tap][pxl][2] = wy*(1.f-wx)*vy1*vx0;
        bw[tap][pxl][3] = wy*wx*vy1*vx1;
        bi[tap][pxl][0] = (y0c*WW + x0c)*CIN;
        bi[tap][pxl][1] = (y0c*WW + x1c)*CIN;
        bi[tap][pxl][2] = (y1c*WW + x0c)*CIN;
        bi[tap][pxl][3] = (y1c*WW + x1c)*CIN;
    }
    __syncthreads();

    // ---------- phase 3: main deformable GEMM, reg-prefetched gather, 1 barrier/chunk ----------
    f32x4 acc[4][4];
    #pragma unroll
    for (int mi = 0; mi < 4; ++mi)
        #pragma unroll
        for (int ni = 0; ni < 4; ++ni)
            acc[mi][ni] = (f32x4){0.f,0.f,0.f,0.f};

    const int mt0 = wv * 4;
    float4 wt;
    uint4 ca, cbv, ccv, cdv;
    {   // preload corners + weights for chunk 0
        wt = *(const float4*)bw[0][px];
        const int4 ix = *(const int4*)bi[0][px];
        const int c0 = cg*8;
        ca  = *(const uint4*)(xbase + ix.x + c0);
        cbv = *(const uint4*)(xbase + ix.y + c0);
        ccv = *(const uint4*)(xbase + ix.z + c0);
        cdv = *(const uint4*)(xbase + ix.w + c0);
    }

    #pragma unroll 2
    for (int kc = 0; kc < NKC; ++kc) {
        // A fragments for this chunk (issued early, used after barrier)
        bf16x8 afr[4];
        #pragma unroll
        for (int mi = 0; mi < 4; ++mi)
            afr[mi] = *(const bf16x8*)(wmain + ((size_t)(kc*16 + mt0 + mi)*64 + lane)*8);
        // blend current corners and stage to LDS
        uint4 r;
        r.x = blendpack(ca.x, cbv.x, ccv.x, cdv.x, wt.x, wt.y, wt.z, wt.w);
        r.y = blendpack(ca.y, cbv.y, ccv.y, cdv.y, wt.x, wt.y, wt.z, wt.w);
        r.z = blendpack(ca.z, cbv.z, ccv.z, cdv.z, wt.x, wt.y, wt.z, wt.w);
        r.w = blendpack(ca.w, cbv.w, ccv.w, cdv.w, wt.x, wt.y, wt.z, wt.w);
        *(uint4*)&ldsB[kc&1][px*LDSROW + cg*8] = r;
        // prefetch next chunk's corners (vmcnt floats across the barrier)
        if (kc+1 < NKC) {
            const int tapn = (kc+1) >> 3;
            const int c0n = ((kc+1) & 7)*32 + cg*8;
            const float4 wtn = *(const float4*)bw[tapn][px];
            const int4 ixn = *(const int4*)bi[tapn][px];
            ca  = *(const uint4*)(xbase + ixn.x + c0n);
            cbv = *(const uint4*)(xbase + ixn.y + c0n);
            ccv = *(const uint4*)(xbase + ixn.z + c0n);
            cdv = *(const uint4*)(xbase + ixn.w + c0n);
            wt = wtn;
        }
        asm volatile("s_waitcnt lgkmcnt(0)" ::: "memory");
        __builtin_amdgcn_s_barrier();
        bf16x8 bfr[4];
        #pragma unroll
        for (int ni = 0; ni < 4; ++ni)
            bfr[ni] = *(const bf16x8*)&ldsB[kc&1][(ni*16 + (lane&15))*LDSROW + (lane>>4)*8];
        #pragma unroll
        for (int mi = 0; mi < 4; ++mi)
            #pragma unroll
            for (int ni = 0; ni < 4; ++ni)
                acc[mi][ni] = __builtin_amdgcn_mfma_f32_16x16x32_bf16(afr[mi], bfr[ni], acc[mi][ni], 0, 0, 0);
    }

    // epilogue: D[m][n]: col = lane&15 (pixel), row = (lane>>4)*4+j (out channel)
    #pragma unroll
    for (int mi = 0; mi < 4; ++mi) {
        #pragma unroll
        for (int ni = 0; ni < 4; ++ni) {
            const int pxl = ni*16 + (lane & 15);
            #pragma unroll
            for (int j = 0; j < 4; ++j) {
                const int o = (mt0 + mi)*16 + (lane >> 4)*4 + j;
                out[((size_t)bb*COUT + o)*HW + hwb + pxl] = acc[mi][ni][j] + conv_b[o];
            }
        }
    }
}

extern "C" void kernel_launch(void* const* d_in, const int* in_sizes, int n_in,
                              void* d_out, int out_size, void* d_ws, size_t ws_size,
                              hipStream_t stream) {
    const float* x        = (const float*)d_in[0];
    const float* offset_w = (const float*)d_in[1];
    const float* offset_b = (const float*)d_in[2];
    const float* conv_w   = (const float*)d_in[3];
    const float* conv_b   = (const float*)d_in[4];
    float* out = (float*)d_out;

    char* wsb = (char*)d_ws;
    ushort_t* xb    = (ushort_t*)wsb;
    ushort_t* wmain = (ushort_t*)(wsb + (size_t)CB*HW*CIN*2);
    ushort_t* woff  = (ushort_t*)(wsb + (size_t)CB*HW*CIN*2 + (size_t)NKC*16*64*8*2);

    hipLaunchKernelGGL(transpose_x, dim3(CB*(HW/64)), dim3(256), 0, stream, x, xb);
    hipLaunchKernelGGL(pack_w, dim3(324), dim3(256), 0, stream, conv_w, offset_w, wmain, woff);
    hipLaunchKernelGGL(deform_main, dim3(CB*(HW/64)), dim3(256), 0, stream,
                       xb, wmain, woff, offset_b, conv_b, out);
}

// Round 4
// 157.996 us; speedup vs baseline: 1.3037x; 1.1264x over previous
//
#include <hip/hip_runtime.h>

#define CB 4
#define CIN 256
#define COUT 256
#define HH 80
#define WW 80
#define HW (HH*WW)
#define K2 9
#define NKC 72          // K chunks = 2304/32
#define LDSROW 56       // phase-3 B-tile row stride (elems); uniform-8 on b128 (optimal)
#define NSTRIP (HW/64)  // 100 strips per batch image
#define NBLK (CB*NSTRIP)

typedef unsigned short ushort_t;
typedef __attribute__((ext_vector_type(8))) short bf16x8;
typedef __attribute__((ext_vector_type(4))) float f32x4;

__device__ __forceinline__ ushort_t f2bf(float f) {
    unsigned int b = __float_as_uint(f);
    b += 0x7fffu + ((b >> 16) & 1u);
    return (ushort_t)(b >> 16);
}
__device__ __forceinline__ float bflo(unsigned int u) { return __uint_as_float(u << 16); }
__device__ __forceinline__ float bfhi(unsigned int u) { return __uint_as_float(u & 0xffff0000u); }

__device__ __forceinline__ unsigned int blendpack(unsigned int a, unsigned int b,
                                                  unsigned int c, unsigned int d,
                                                  float w0, float w1, float w2, float w3) {
    float lo = w0*bflo(a) + w1*bflo(b) + w2*bflo(c) + w3*bflo(d);
    float hi = w0*bfhi(a) + w1*bfhi(b) + w2*bfhi(c) + w3*bfhi(d);
    unsigned int r;
    asm("v_cvt_pk_bf16_f32 %0, %1, %2" : "=v"(r) : "v"(lo), "v"(hi));
    return r;
}

// Fused prepass: blocks [0,400) transpose NCHW fp32 -> NHWC bf16; blocks [400,724) pack weights.
__global__ __launch_bounds__(256) void prep(const float* __restrict__ x,
                                            const float* __restrict__ conv_w,
                                            const float* __restrict__ offset_w,
                                            ushort_t* __restrict__ xb,
                                            ushort_t* __restrict__ wmain,
                                            ushort_t* __restrict__ woff) {
    __shared__ ushort_t tile[64*256];
    const int tid = threadIdx.x;
    if (blockIdx.x < NBLK) {
        const int b = blockIdx.x / NSTRIP;
        const int hw0 = (blockIdx.x % NSTRIP) * 64;
        const int px4 = (tid & 15) * 4;
        const int cb0 = tid >> 4;
        const float* xp = x + (size_t)b*CIN*HW + hw0 + px4;
        #pragma unroll
        for (int p = 0; p < 16; ++p) {
            const int c = cb0 * 16 + p;
            const float4 v = *(const float4*)(xp + (size_t)c*HW);
            const int blk = c >> 3, sub = c & 7;
            tile[(px4+0)*256 + (((blk) ^ ((px4+0)&31))<<3) + sub] = f2bf(v.x);
            tile[(px4+1)*256 + (((blk) ^ ((px4+1)&31))<<3) + sub] = f2bf(v.y);
            tile[(px4+2)*256 + (((blk) ^ ((px4+2)&31))<<3) + sub] = f2bf(v.z);
            tile[(px4+3)*256 + (((blk) ^ ((px4+3)&31))<<3) + sub] = f2bf(v.w);
        }
        __syncthreads();
        const int g = tid & 31;
        #pragma unroll
        for (int p = 0; p < 8; ++p) {
            const int px = (tid >> 5) + p*8;
            const uint4 r = *(const uint4*)&tile[px*256 + ((g ^ (px&31))<<3)];
            *(uint4*)&xb[((size_t)b*HW + hw0 + px)*CIN + g*8] = r;
        }
    } else {
        const int t = (blockIdx.x - NBLK) * 256 + tid;
        if (t < NKC*16*64) {
            const int kc = t >> 10;
            const int mt = (t >> 6) & 15;
            const int l  = t & 63;
            const int m  = mt*16 + (l & 15);
            const int kb = kc*32 + ((l >> 4) << 3);
            ushort_t v[8];
            #pragma unroll
            for (int i = 0; i < 8; ++i) {
                const int kg = kb + i;
                const int tap = kg >> 8;
                const int c = kg & 255;
                v[i] = f2bf(conv_w[(size_t)(m*CIN + c)*K2 + tap]);
            }
            uint4 r;
            r.x = v[0] | ((unsigned)v[1] << 16);
            r.y = v[2] | ((unsigned)v[3] << 16);
            r.z = v[4] | ((unsigned)v[5] << 16);
            r.w = v[6] | ((unsigned)v[7] << 16);
            *(uint4*)&wmain[(size_t)t*8] = r;
        } else if (t < NKC*16*64 + NKC*2*64) {
            const int t2 = t - NKC*16*64;
            const int kc = t2 >> 7;
            const int mt = (t2 >> 6) & 1;
            const int l  = t2 & 63;
            const int m  = mt*16 + (l & 15);
            const int kb = kc*32 + ((l >> 4) << 3);
            ushort_t v[8];
            #pragma unroll
            for (int i = 0; i < 8; ++i) {
                const int kg = kb + i;
                const int tap = kg >> 8;
                const int c = kg & 255;
                v[i] = (m < 18) ? f2bf(offset_w[(size_t)(m*CIN + c)*K2 + tap]) : (ushort_t)0;
            }
            uint4 r;
            r.x = v[0] | ((unsigned)v[1] << 16);
            r.y = v[2] | ((unsigned)v[3] << 16);
            r.z = v[4] | ((unsigned)v[5] << 16);
            r.w = v[6] | ((unsigned)v[7] << 16);
            *(uint4*)&woff[(size_t)t2*8] = r;
        }
    }
}

// ---- phase-3 pipelined step (BUF = compile-time 0/1) ----
template<int BUF>
__device__ __forceinline__ void p3step(int kc, const ushort_t* __restrict__ xbase,
                                       const ushort_t* __restrict__ wmain,
                                       ushort_t* __restrict__ ldsB,
                                       const float (&bw)[K2][64][4], const int (&bi)[K2][64][4],
                                       uint4 &A0, uint4 &A1, uint4 &A2, uint4 &A3, float4 &wtA,
                                       bf16x8 (&afU)[4], bf16x8 (&afI)[4], f32x4 (&acc)[4][4],
                                       int pxg, int cg, int lane, int mt0) {
    // 1. table read for kc+2 (LDS)
    float4 wtT; int4 ixT;
    const bool have = (kc + 2) < NKC;
    if (have) {
        const int tapT = (kc + 2) >> 3;
        wtT = *(const float4*)bw[tapT][pxg];
        ixT = *(const int4*)bi[tapT][pxg];
    }
    // 2. A-fragments for kc+1 (global, L2-hot)
    if (kc + 1 < NKC) {
        #pragma unroll
        for (int mi = 0; mi < 4; ++mi)
            afI[mi] = *(const bf16x8*)(wmain + ((size_t)((kc+1)*16 + mt0 + mi)*64 + lane)*8);
    }
    // 3. blend current corners (arrived 2 chunks ago) -> LDS
    uint4 r;
    r.x = blendpack(A0.x, A1.x, A2.x, A3.x, wtA.x, wtA.y, wtA.z, wtA.w);
    r.y = blendpack(A0.y, A1.y, A2.y, A3.y, wtA.x, wtA.y, wtA.z, wtA.w);
    r.z = blendpack(A0.z, A1.z, A2.z, A3.z, wtA.x, wtA.y, wtA.z, wtA.w);
    r.w = blendpack(A0.w, A1.w, A2.w, A3.w, wtA.x, wtA.y, wtA.z, wtA.w);
    *(uint4*)&ldsB[BUF*64*LDSROW + pxg*LDSROW + cg*8] = r;
    // 4. issue corner loads for kc+2 (vmcnt floats across the barrier)
    if (have) {
        const int c0n = ((kc+2) & 7)*32 + cg*8;
        A0 = *(const uint4*)(xbase + ixT.x + c0n);
        A1 = *(const uint4*)(xbase + ixT.y + c0n);
        A2 = *(const uint4*)(xbase + ixT.z + c0n);
        A3 = *(const uint4*)(xbase + ixT.w + c0n);
        wtA = wtT;
    }
    // 5. LDS drain + barrier (no vmcnt drain)
    asm volatile("s_waitcnt lgkmcnt(0)" ::: "memory");
    __builtin_amdgcn_s_barrier();
    // 6. B fragments + 16 MFMA
    bf16x8 bfr[4];
    #pragma unroll
    for (int ni = 0; ni < 4; ++ni)
        bfr[ni] = *(const bf16x8*)&ldsB[BUF*64*LDSROW + (ni*16 + (lane&15))*LDSROW + (lane>>4)*8];
    #pragma unroll
    for (int mi = 0; mi < 4; ++mi)
        #pragma unroll
        for (int ni = 0; ni < 4; ++ni)
            acc[mi][ni] = __builtin_amdgcn_mfma_f32_16x16x32_bf16(afU[mi], bfr[ni], acc[mi][ni], 0, 0, 0);
}

__global__ __launch_bounds__(256) void deform_main(const ushort_t* __restrict__ xb,
                                                   const ushort_t* __restrict__ wmain,
                                                   const ushort_t* __restrict__ woff,
                                                   const float* __restrict__ offset_b,
                                                   const float* __restrict__ conv_b,
                                                   float* __restrict__ out) {
    // LDS pool: phase1 view = 4 waves x 2 bufs x [32][40] bf16 (20480B)
    //           phase3 view = [2][64*LDSROW] bf16 (14336B)
    __shared__ __align__(16) char lds_pool[20480];
    __shared__ float off_lds[18][64];
    __shared__ float bw[K2][64][4];
    __shared__ int   bi[K2][64][4];

    const int tid = threadIdx.x;
    const int lane = tid & 63;
    const int wv = tid >> 6;
    // XCD-aware strip swizzle: 400 % 8 == 0, q = 50 -> bijective; each XCD owns 50 contiguous strips
    const int sb = (blockIdx.x & 7) * (NBLK/8) + (blockIdx.x >> 3);
    const int bb = sb / NSTRIP;
    const int hwb = (sb % NSTRIP) * 64;
    const ushort_t* xbase = xb + (size_t)bb * HW * CIN;
    const int pxg = tid >> 2, cg = tid & 3;

    // ---------- phase 1: offset conv, wave-private LDS tiles, ZERO barriers, PF=2 ----------
    {
        const int mt = wv >> 1;            // 0..1 (m half)
        const int p0 = (wv & 1) * 32;      // pixel half base
        ushort_t* myB = (ushort_t*)lds_pool + wv * 2560;   // 2 bufs x 32 x 40
        f32x4 a0 = {0.f,0.f,0.f,0.f}, a1 = {0.f,0.f,0.f,0.f};
        const int pxl = lane >> 1;         // 0..31 local pixel
        const int ch  = lane & 1;          // 16-chan half
        const int hw = hwb + p0 + pxl;
        const int ph = hw / WW, pw = hw - ph*WW;

        uint4 u0a, u0b, u1a, u1b;
        #define P1LOAD(UA, UB, KC_) { \
            const int tap_ = (KC_) >> 3; \
            const int c0_ = ((KC_) & 7)*32 + ch*16; \
            const int yy_ = ph + tap_/3 - 1, xx_ = pw + tap_%3 - 1; \
            UA = make_uint4(0u,0u,0u,0u); UB = make_uint4(0u,0u,0u,0u); \
            if (yy_ >= 0 && yy_ < HH && xx_ >= 0 && xx_ < WW) { \
                const ushort_t* p_ = xbase + (yy_*WW + xx_)*CIN + c0_; \
                UA = *(const uint4*)p_; UB = *(const uint4*)(p_ + 8); } }

        P1LOAD(u0a, u0b, 0);
        P1LOAD(u1a, u1b, 1);
        for (int kp = 0; kp < NKC/2; ++kp) {
            {
                const int kc = 2*kp;
                const bf16x8 af = *(const bf16x8*)(woff + ((size_t)(kc*2 + mt)*64 + lane)*8);
                ushort_t* wb = myB + pxl*40 + ch*16;
                *(uint4*)wb = u0a;
                *(uint4*)(wb + 8) = u0b;
                if (kp + 1 < NKC/2) P1LOAD(u0a, u0b, 2*kp + 2);
                const bf16x8 b0 = *(const bf16x8*)(myB + (lane&15)*40 + (lane>>4)*8);
                const bf16x8 b1 = *(const bf16x8*)(myB + (16 + (lane&15))*40 + (lane>>4)*8);
                a0 = __builtin_amdgcn_mfma_f32_16x16x32_bf16(af, b0, a0, 0, 0, 0);
                a1 = __builtin_amdgcn_mfma_f32_16x16x32_bf16(af, b1, a1, 0, 0, 0);
            }
            {
                const int kc = 2*kp + 1;
                const bf16x8 af = *(const bf16x8*)(woff + ((size_t)(kc*2 + mt)*64 + lane)*8);
                ushort_t* wb = myB + 1280 + pxl*40 + ch*16;
                *(uint4*)wb = u1a;
                *(uint4*)(wb + 8) = u1b;
                if (kp + 1 < NKC/2) P1LOAD(u1a, u1b, 2*kp + 3);
                const bf16x8 b0 = *(const bf16x8*)(myB + 1280 + (lane&15)*40 + (lane>>4)*8);
                const bf16x8 b1 = *(const bf16x8*)(myB + 1280 + (16 + (lane&15))*40 + (lane>>4)*8);
                a0 = __builtin_amdgcn_mfma_f32_16x16x32_bf16(af, b0, a0, 0, 0, 0);
                a1 = __builtin_amdgcn_mfma_f32_16x16x32_bf16(af, b1, a1, 0, 0, 0);
            }
        }
        #undef P1LOAD
        const int r0 = (lane >> 4) * 4;
        #pragma unroll
        for (int j = 0; j < 4; ++j) {
            const int oc = mt*16 + r0 + j;
            if (oc < 18) {
                const float ob = offset_b[oc];
                off_lds[oc][p0 + (lane & 15)]      = a0[j] + ob;
                off_lds[oc][p0 + 16 + (lane & 15)] = a1[j] + ob;
            }
        }
    }
    __syncthreads();

    // ---------- phase 2: bilinear weights/indices ----------
    for (int it = tid; it < K2*64; it += 256) {
        const int tap = it >> 6, pxl = it & 63;
        const int hw = hwb + pxl;
        const int ph = hw / WW, pw = hw - ph*WW;
        const float dy = off_lds[tap*2][pxl];
        const float dx = off_lds[tap*2 + 1][pxl];
        const float py  = (float)(ph + tap/3 - 1) + dy;
        const float pxx = (float)(pw + tap%3 - 1) + dx;
        const float y0f = floorf(py), x0f = floorf(pxx);
        const float wy = py - y0f, wx = pxx - x0f;
        const int y0 = (int)y0f, x0 = (int)x0f;
        const int y1 = y0 + 1, x1 = x0 + 1;
        const float vy0 = (y0 >= 0 && y0 < HH) ? 1.f : 0.f;
        const float vy1 = (y1 >= 0 && y1 < HH) ? 1.f : 0.f;
        const float vx0 = (x0 >= 0 && x0 < WW) ? 1.f : 0.f;
        const float vx1 = (x1 >= 0 && x1 < WW) ? 1.f : 0.f;
        const int y0c = min(max(y0, 0), HH-1), y1c = min(max(y1, 0), HH-1);
        const int x0c = min(max(x0, 0), WW-1), x1c = min(max(x1, 0), WW-1);
        bw[tap][pxl][0] = (1.f-wy)*(1.f-wx)*vy0*vx0;
        bw[tap][pxl][1] = (1.f-wy)*wx*vy0*vx1;
        bw[tap][pxl][2] = wy*(1.f-wx)*vy1*vx0;
        bw[tap][pxl][3] = wy*wx*vy1*vx1;
        bi[tap][pxl][0] = (y0c*WW + x0c)*CIN;
        bi[tap][pxl][1] = (y0c*WW + x1c)*CIN;
        bi[tap][pxl][2] = (y1c*WW + x0c)*CIN;
        bi[tap][pxl][3] = (y1c*WW + x1c)*CIN;
    }
    __syncthreads();

    // ---------- phase 3: main deformable GEMM, PF=2 corners + PF=1 A-frags ----------
    f32x4 acc[4][4];
    #pragma unroll
    for (int mi = 0; mi < 4; ++mi)
        #pragma unroll
        for (int ni = 0; ni < 4; ++ni)
            acc[mi][ni] = (f32x4){0.f,0.f,0.f,0.f};

    ushort_t* ldsB = (ushort_t*)lds_pool;
    const int mt0 = wv * 4;
    float4 wtA, wtB;
    uint4 A0, A1, A2, A3, B0, B1, B2, B3;
    bf16x8 afA[4], afB[4];
    {   // prologue: corners(0)->A, corners(1)->B, A-frags(0)->afA
        wtA = *(const float4*)bw[0][pxg];
        const int4 ix0 = *(const int4*)bi[0][pxg];
        const int c00 = cg*8;
        A0 = *(const uint4*)(xbase + ix0.x + c00);
        A1 = *(const uint4*)(xbase + ix0.y + c00);
        A2 = *(const uint4*)(xbase + ix0.z + c00);
        A3 = *(const uint4*)(xbase + ix0.w + c00);
        wtB = *(const float4*)bw[0][pxg];
        const int4 ix1 = *(const int4*)bi[0][pxg];
        const int c01 = 32 + cg*8;
        B0 = *(const uint4*)(xbase + ix1.x + c01);
        B1 = *(const uint4*)(xbase + ix1.y + c01);
        B2 = *(const uint4*)(xbase + ix1.z + c01);
        B3 = *(const uint4*)(xbase + ix1.w + c01);
        #pragma unroll
        for (int mi = 0; mi < 4; ++mi)
            afA[mi] = *(const bf16x8*)(wmain + ((size_t)(mt0 + mi)*64 + lane)*8);
    }
    for (int kp = 0; kp < NKC/2; ++kp) {
        p3step<0>(2*kp,     xbase, wmain, ldsB, bw, bi, A0, A1, A2, A3, wtA, afA, afB, acc, pxg, cg, lane, mt0);
        p3step<1>(2*kp + 1, xbase, wmain, ldsB, bw, bi, B0, B1, B2, B3, wtB, afB, afA, acc, pxg, cg, lane, mt0);
    }

    // epilogue: D[m][n]: col = lane&15 (pixel), row = (lane>>4)*4+j (out channel)
    #pragma unroll
    for (int mi = 0; mi < 4; ++mi) {
        #pragma unroll
        for (int ni = 0; ni < 4; ++ni) {
            const int pxl = ni*16 + (lane & 15);
            #pragma unroll
            for (int j = 0; j < 4; ++j) {
                const int o = (mt0 + mi)*16 + (lane >> 4)*4 + j;
                out[((size_t)bb*COUT + o)*HW + hwb + pxl] = acc[mi][ni][j] + conv_b[o];
            }
        }
    }
}

extern "C" void kernel_launch(void* const* d_in, const int* in_sizes, int n_in,
                              void* d_out, int out_size, void* d_ws, size_t ws_size,
                              hipStream_t stream) {
    const float* x        = (const float*)d_in[0];
    const float* offset_w = (const float*)d_in[1];
    const float* offset_b = (const float*)d_in[2];
    const float* conv_w   = (const float*)d_in[3];
    const float* conv_b   = (const float*)d_in[4];
    float* out = (float*)d_out;

    char* wsb = (char*)d_ws;
    ushort_t* xb    = (ushort_t*)wsb;
    ushort_t* wmain = (ushort_t*)(wsb + (size_t)CB*HW*CIN*2);
    ushort_t* woff  = (ushort_t*)(wsb + (size_t)CB*HW*CIN*2 + (size_t)NKC*16*64*8*2);

    hipLaunchKernelGGL(prep, dim3(NBLK + 324), dim3(256), 0, stream,
                       x, conv_w, offset_w, xb, wmain, woff);
    hipLaunchKernelGGL(deform_main, dim3(NBLK), dim3(256), 0, stream,
                       xb, wmain, woff, offset_b, conv_b, out);
}